// Round 1
// baseline (165.663 us; speedup 1.0000x reference)
//
#include <hip/hip_runtime.h>
#include <stdint.h>

#define SEQ 8192
#define DIN 768
#define DOUT 128

typedef __attribute__((ext_vector_type(8))) short short8;
typedef __attribute__((ext_vector_type(8))) unsigned short ushort8v;
typedef __attribute__((ext_vector_type(4))) float f32x4;

// softmax exp base conversion: (1/sqrt(128)) * log2(e), folded into wq at convert time
#define CEXPF (1.4426950408889634f * 0.08838834764831845f)

#if __has_builtin(__builtin_amdgcn_exp2f)
#define EXP2(x) __builtin_amdgcn_exp2f(x)
#else
#define EXP2(x) __builtin_exp2f(x)
#endif

// round-half-up f32->bf16 (2 VALU ops)
__device__ __forceinline__ unsigned short f2bf(float f) {
  return (unsigned short)((__float_as_uint(f) + 0x8000u) >> 16);
}

// async global->LDS DMA, 16B per lane.  LDS dest = wave-uniform base + lane*16.
__device__ __forceinline__ void gload_lds16(const void* g, void* l) {
  __builtin_amdgcn_global_load_lds(
      (const __attribute__((address_space(1))) void*)g,
      (__attribute__((address_space(3))) void*)l, 16, 0, 0);
}

// ---------------------------------------------------------------------------
// Kernel 0: convert W's to bf16 once.  Wb[z][outcol][din], wq scaled by CEXPF.
// grid 288, block 256, 4 elems/thread.
// ---------------------------------------------------------------------------
__global__ void wconv_kernel(const float* __restrict__ wq,
                             const float* __restrict__ wk,
                             const float* __restrict__ wv,
                             unsigned short* __restrict__ Wb) {
  int idx4 = (blockIdx.x * 256 + threadIdx.x) * 4;   // < 3*128*768 = 294912
  int z = idx4 / (DOUT * DIN);
  int rem = idx4 - z * (DOUT * DIN);
  const float* src = (z == 0) ? wq : (z == 1) ? wk : wv;
  float4 v = *(const float4*)(src + rem);
  float sc = (z == 0) ? CEXPF : 1.0f;
  ushort4 o;
  o.x = f2bf(v.x * sc); o.y = f2bf(v.y * sc);
  o.z = f2bf(v.z * sc); o.w = f2bf(v.w * sc);
  *(ushort4*)(Wb + idx4) = o;
}

// ---------------------------------------------------------------------------
// Kernel A: QKV projection.  grid (256, 3) = 768 blocks (3/CU), block 256.
// Block = 32 rows x 128 outcols.  A=W (direct global b128 from L2), B=x loaded
// DIRECTLY per-lane as fp32 and converted in-reg (no LDS staging, ZERO barriers
// in the K-loop -> compiler pipelines loads across iterations).
// z=0 -> Q (scale folded in Wb), z=1 -> K, z=2 -> Vt[128][8192] via LDS transpose.
// ---------------------------------------------------------------------------
__launch_bounds__(256, 3)
__global__ void qkv_kernel(const float* __restrict__ x,
                           const unsigned short* __restrict__ Wb,
                           unsigned short* __restrict__ Qb,
                           unsigned short* __restrict__ Kb,
                           unsigned short* __restrict__ Vtb) {
  __shared__ unsigned short smem[4352];    // ct[32][136] for z==2 transpose epilogue

  const int t    = threadIdx.x;
  const int w    = t >> 6;
  const int lane = t & 63;
  const int g    = lane >> 4;
  const int r    = lane & 15;
  const int z    = blockIdx.y;
  const int m0   = blockIdx.x * 32;
  const unsigned short* Wz = Wb + (size_t)z * DOUT * DIN;

  f32x4 acc[2][2];
#pragma unroll
  for (int i = 0; i < 2; i++)
#pragma unroll
    for (int j = 0; j < 2; j++) acc[i][j] = 0.f;

#pragma unroll 2
  for (int kb = 0; kb < DIN; kb += 32) {
    // A-frags straight from global (L2-resident Wb): A[m=outcol][k]
    short8 af[2];
#pragma unroll
    for (int mt = 0; mt < 2; mt++)
      af[mt] = *(const short8*)(Wz + (size_t)(w * 32 + mt * 16 + r) * DIN + kb + g * 8);
    // B-frags: lane (g,r) reads 8 consecutive fp32 of x row nt*16+r, convert in-reg
    short8 bf[2];
#pragma unroll
    for (int nt = 0; nt < 2; nt++) {
      const float* xp = x + (size_t)(m0 + nt * 16 + r) * DIN + kb + g * 8;
      float4 lo = *(const float4*)xp;
      float4 hi = *(const float4*)(xp + 4);
      short8 b;
      b[0] = (short)f2bf(lo.x); b[1] = (short)f2bf(lo.y);
      b[2] = (short)f2bf(lo.z); b[3] = (short)f2bf(lo.w);
      b[4] = (short)f2bf(hi.x); b[5] = (short)f2bf(hi.y);
      b[6] = (short)f2bf(hi.z); b[7] = (short)f2bf(hi.w);
      bf[nt] = b;
    }
#pragma unroll
    for (int mt = 0; mt < 2; mt++)
#pragma unroll
      for (int nt = 0; nt < 2; nt++)
        acc[mt][nt] = __builtin_amdgcn_mfma_f32_16x16x32_bf16(af[mt], bf[nt], acc[mt][nt], 0, 0, 0);
  }

  // D[m = w*32+mt*16+g*4+reg (outcol)][n = nt*16+r (row)] — 4 consecutive outcols/lane
  if (z < 2) {
    unsigned short* out = (z == 0) ? Qb : Kb;
#pragma unroll
    for (int mt = 0; mt < 2; mt++)
#pragma unroll
      for (int nt = 0; nt < 2; nt++) {
        ushort4 o;
        o.x = f2bf(acc[mt][nt][0]); o.y = f2bf(acc[mt][nt][1]);
        o.z = f2bf(acc[mt][nt][2]); o.w = f2bf(acc[mt][nt][3]);
        *(ushort4*)(out + (size_t)(m0 + nt * 16 + r) * DOUT + w * 32 + mt * 16 + g * 4) = o;
      }
  } else {
    unsigned short* ct = smem;   // [32][136]
#pragma unroll
    for (int mt = 0; mt < 2; mt++)
#pragma unroll
      for (int nt = 0; nt < 2; nt++) {
        ushort4 o;
        o.x = f2bf(acc[mt][nt][0]); o.y = f2bf(acc[mt][nt][1]);
        o.z = f2bf(acc[mt][nt][2]); o.w = f2bf(acc[mt][nt][3]);
        *(ushort4*)&ct[(nt * 16 + r) * 136 + w * 32 + mt * 16 + g * 4] = o;
      }
    __syncthreads();
    int col  = t >> 1;           // 0..127
    int half = (t & 1) * 16;     // 0 / 16
#pragma unroll
    for (int h2 = 0; h2 < 2; h2++) {
      ushort8v a;
#pragma unroll
      for (int i = 0; i < 8; i++) a[i] = ct[(half + h2 * 8 + i) * 136 + col];
      *(ushort8v*)(Vtb + (size_t)col * SEQ + m0 + half + h2 * 8) = a;
    }
  }
}

// ---------------------------------------------------------------------------
// Kernel B: flash attention (no online max; scale folded into Q).
// grid (64 qblocks, 8 splits), block 256 (4 waves), wave = 32 q-rows, BN=64.
// S^T = K·Q^T so P^T C-layout packs to b64 LDS writes; staging via
// global_load_lds w/ source-side XOR swizzle.
// Pipelined single-buffer rotation (counted vmcnt, raw s_barrier — no drains):
//   QK(t) -> vmcnt(0)[V(t) landed] -> bar -> issue K(t+1) -> PV(t) -> bar ->
//   issue V(t+1) -> vmcnt(4)[K(t+1) landed, V(t+1) in flight] -> bar
// ---------------------------------------------------------------------------
__launch_bounds__(256, 2)
__global__ void attn_kernel(const unsigned short* __restrict__ Qb,
                            const unsigned short* __restrict__ Kb,
                            const unsigned short* __restrict__ Vtb,
                            float* __restrict__ Opart,
                            float* __restrict__ lpart) {
  __shared__ unsigned char lds[51200];
  unsigned char* Kl = lds;           // [64][128] bf16, 16B chunks XOR-swizzled by row&15
  unsigned char* Vl = lds + 16384;   // [128][64] bf16, 16B chunks XOR-swizzled by d&7

  const int t    = threadIdx.x;
  const int wave = t >> 6;
  const int lane = t & 63;
  const int g    = lane >> 4;
  const int r    = lane & 15;
  unsigned short* Pl = (unsigned short*)(lds + 32768 + wave * 4608);  // [32 q][72 kv]

  const int qb = blockIdx.x;
  const int sp = blockIdx.y;
  const int q0 = qb * 128 + wave * 32;
  const int kvbase = sp * 1024;

  // async staging helpers: 4 chunks K / 4 chunks V per wave, swizzle on source
  auto stageK = [&](int kv0) {
#pragma unroll
    for (int c = 0; c < 4; c++) {
      int idx = (wave * 4 + c) * 64 + lane;          // 0..1023
      int krow = idx >> 4, kch = idx & 15;
      gload_lds16(Kb + ((size_t)(kv0 + krow) << 7) + ((kch ^ (krow & 15)) << 3),
                  Kl + ((wave * 4 + c) << 10) + (lane << 4));
    }
  };
  auto stageV = [&](int kv0) {
#pragma unroll
    for (int c = 0; c < 4; c++) {
      int idx = (wave * 4 + c) * 64 + lane;          // 0..1023
      int d = idx >> 3, c2 = idx & 7;
      gload_lds16(Vtb + (size_t)d * SEQ + kv0 + ((c2 ^ (d & 7)) << 3),
                  Vl + ((wave * 4 + c) << 10) + (lane << 4));
    }
  };

  // Q B-frags: B[k=din][n=q], n=r, k=g*8+j — contiguous from Qb
  short8 qf[2][4];
#pragma unroll
  for (int nt = 0; nt < 2; nt++)
#pragma unroll
    for (int kc = 0; kc < 4; kc++)
      qf[nt][kc] = *(const short8*)(Qb + (size_t)(q0 + nt * 16 + r) * DOUT + kc * 32 + g * 8);

  // ones B-frag: column n==0 (r==0) holds 1.0bf16
  short8 onesf;
#pragma unroll
  for (int j = 0; j < 8; j++) onesf[j] = (r == 0) ? (short)0x3F80 : (short)0;

  f32x4 oacc[2][8];
  f32x4 lacc[2];
#pragma unroll
  for (int st = 0; st < 2; st++) {
    lacc[st] = 0.f;
#pragma unroll
    for (int n = 0; n < 8; n++) oacc[st][n] = 0.f;
  }

  // prologue: stage tile 0 fully
  stageK(kvbase);
  stageV(kvbase);
  asm volatile("s_waitcnt vmcnt(0)" ::: "memory");
  __builtin_amdgcn_s_barrier();
  asm volatile("" ::: "memory");

#pragma unroll 1
  for (int it = 0; it < 16; it++) {
    // ---- S^T = K Q^T : A=kf (m=kv), B=qf (n=q).  sf[mt][nt] ----
    f32x4 sf[4][2];
#pragma unroll
    for (int mt = 0; mt < 4; mt++)
#pragma unroll
      for (int nt = 0; nt < 2; nt++) sf[mt][nt] = 0.f;
    __builtin_amdgcn_s_setprio(1);
#pragma unroll
    for (int mt = 0; mt < 4; mt++) {
      int row = mt * 16 + r;
#pragma unroll
      for (int kc = 0; kc < 4; kc++) {
        short8 kf = *(const short8*)(Kl + row * 256 + (((kc * 4 + g) ^ (row & 15)) << 4));
        sf[mt][0] = __builtin_amdgcn_mfma_f32_16x16x32_bf16(kf, qf[0][kc], sf[mt][0], 0, 0, 0);
        sf[mt][1] = __builtin_amdgcn_mfma_f32_16x16x32_bf16(kf, qf[1][kc], sf[mt][1], 0, 0, 0);
      }
    }
    __builtin_amdgcn_s_setprio(0);

    // ---- p = exp2(s); P^T lane holds 4 consecutive kv -> packed b64 writes ----
#pragma unroll
    for (int mt = 0; mt < 4; mt++)
#pragma unroll
      for (int nt = 0; nt < 2; nt++) {
        ushort4 p;
        p.x = f2bf(EXP2(sf[mt][nt][0]));
        p.y = f2bf(EXP2(sf[mt][nt][1]));
        p.z = f2bf(EXP2(sf[mt][nt][2]));
        p.w = f2bf(EXP2(sf[mt][nt][3]));
        *(ushort4*)(Pl + (nt * 16 + r) * 72 + mt * 16 + g * 4) = p;
      }
    short8 pf[2][2];
#pragma unroll
    for (int st = 0; st < 2; st++)
#pragma unroll
      for (int c2 = 0; c2 < 2; c2++)
        pf[st][c2] = *(const short8*)(Pl + (st * 16 + r) * 72 + c2 * 32 + g * 8);

    // own V(t) loads are the only outstanding VMEM -> drain them, then release Kl
    asm volatile("s_waitcnt vmcnt(0)" ::: "memory");
    __builtin_amdgcn_s_barrier();          // A: V(t) ready everywhere, Kl free
    asm volatile("" ::: "memory");
    if (it < 15) stageK(kvbase + (it + 1) * 64);   // flies under PV

    // ---- O += P V ; l += P @ ones ----
    __builtin_amdgcn_s_setprio(1);
#pragma unroll
    for (int nt = 0; nt < 8; nt++) {
      int d = nt * 16 + r;
#pragma unroll
      for (int c2 = 0; c2 < 2; c2++) {
        short8 vf = *(const short8*)(Vl + d * 128 + (((c2 * 4 + g) ^ (d & 7)) << 4));
        oacc[0][nt] = __builtin_amdgcn_mfma_f32_16x16x32_bf16(pf[0][c2], vf, oacc[0][nt], 0, 0, 0);
        oacc[1][nt] = __builtin_amdgcn_mfma_f32_16x16x32_bf16(pf[1][c2], vf, oacc[1][nt], 0, 0, 0);
      }
    }
#pragma unroll
    for (int st = 0; st < 2; st++) {
      lacc[st] = __builtin_amdgcn_mfma_f32_16x16x32_bf16(pf[st][0], onesf, lacc[st], 0, 0, 0);
      lacc[st] = __builtin_amdgcn_mfma_f32_16x16x32_bf16(pf[st][1], onesf, lacc[st], 0, 0, 0);
    }
    __builtin_amdgcn_s_setprio(0);

    asm volatile("" ::: "memory");
    __builtin_amdgcn_s_barrier();          // B: Vl free
    asm volatile("" ::: "memory");
    if (it < 15) {
      stageV(kvbase + (it + 1) * 64);      // flies under next QK + exp
      asm volatile("s_waitcnt vmcnt(4)" ::: "memory");  // K(t+1) landed, V(t+1) in flight
      __builtin_amdgcn_s_barrier();        // C: Kl(t+1) ready everywhere
      asm volatile("" ::: "memory");
    }
  }

  // ---- write partials ----
  const size_t pbase = (size_t)sp * SEQ;
#pragma unroll
  for (int st = 0; st < 2; st++)
#pragma unroll
    for (int rr = 0; rr < 4; rr++) {
      int qrow = q0 + st * 16 + g * 4 + rr;
#pragma unroll
      for (int nt = 0; nt < 8; nt++)
        Opart[(pbase + qrow) * DOUT + nt * 16 + r] = oacc[st][nt][rr];
      if (r == 0) lpart[pbase + qrow] = lacc[st][rr];
    }
}

// ---------------------------------------------------------------------------
// Kernel C: combine 8 KV-split partials (plain sum + normalize).
// ---------------------------------------------------------------------------
__global__ void combine_kernel(const float* __restrict__ Opart,
                               const float* __restrict__ lpart,
                               float* __restrict__ out) {
  int idx = blockIdx.x * 256 + threadIdx.x;  // 8192*32
  int s   = idx >> 5;
  int d4  = (idx & 31) * 4;
  float L = 0.f;
  f32x4 acc = 0.f;
#pragma unroll
  for (int p = 0; p < 8; p++) {
    L += lpart[p * SEQ + s];
    acc += *(const f32x4*)(Opart + ((size_t)p * SEQ + s) * DOUT + d4);
  }
  f32x4 res = acc * (1.0f / L);
  *(f32x4*)(out + (size_t)s * DOUT + d4) = res;
}

// ---------------------------------------------------------------------------
extern "C" void kernel_launch(void* const* d_in, const int* in_sizes, int n_in,
                              void* d_out, int out_size, void* d_ws, size_t ws_size,
                              hipStream_t stream) {
  const float* x  = (const float*)d_in[0];
  const float* wq = (const float*)d_in[1];
  const float* wk = (const float*)d_in[2];
  const float* wv = (const float*)d_in[3];
  float* out = (float*)d_out;

  unsigned short* Qb  = (unsigned short*)d_ws;            // 2 MB
  unsigned short* Kb  = Qb + (size_t)SEQ * DOUT;          // 2 MB
  unsigned short* Vtb = Kb + (size_t)SEQ * DOUT;          // 2 MB (transposed)
  float* Opart = (float*)(Vtb + (size_t)SEQ * DOUT);      // 8 * 4 MB
  float* lpart = Opart + (size_t)8 * SEQ * DOUT;          // 256 KB
  // Wb (576 KB bf16) aliases Opart: dead once qkv_kernel finishes, before attn writes
  unsigned short* Wb  = (unsigned short*)Opart;
  if (ws_size < (size_t)(6291456 + 33554432 + 262144)) return;

  wconv_kernel<<<dim3(288), 256, 0, stream>>>(wq, wk, wv, Wb);
  qkv_kernel<<<dim3(256, 3), 256, 0, stream>>>(x, Wb, Qb, Kb, Vtb);
  attn_kernel<<<dim3(64, 8), 256, 0, stream>>>(Qb, Kb, Vtb, Opart, lpart);
  combine_kernel<<<dim3(1024), 256, 0, stream>>>(Opart, lpart, out);
}

// Round 3
// 132.954 us; speedup vs baseline: 1.2460x; 1.2460x over previous
//
#include <hip/hip_runtime.h>
#include <stdint.h>

#define SEQ 8192
#define DIN 768
#define DOUT 128

typedef __attribute__((ext_vector_type(8))) short short8;
typedef __attribute__((ext_vector_type(8))) unsigned short ushort8v;
typedef __attribute__((ext_vector_type(4))) float f32x4;

// softmax exp base conversion: (1/sqrt(128)) * log2(e), folded into wq at convert time
#define CEXPF (1.4426950408889634f * 0.08838834764831845f)

#if __has_builtin(__builtin_amdgcn_exp2f)
#define EXP2(x) __builtin_amdgcn_exp2f(x)
#else
#define EXP2(x) __builtin_exp2f(x)
#endif

// round-half-up f32->bf16 (2 VALU ops)
__device__ __forceinline__ unsigned short f2bf(float f) {
  return (unsigned short)((__float_as_uint(f) + 0x8000u) >> 16);
}

// async global->LDS DMA, 16B per lane.  LDS dest = wave-uniform base + lane*16.
__device__ __forceinline__ void gload_lds16(const void* g, void* l) {
  __builtin_amdgcn_global_load_lds(
      (const __attribute__((address_space(1))) void*)g,
      (__attribute__((address_space(3))) void*)l, 16, 0, 0);
}

// ---------------------------------------------------------------------------
// Kernel 0: convert x AND W's to bf16 once.
// blocks [0,6144): x -> xb (8192*768).  blocks [6144,6432): W -> Wb, wq*CEXPF.
// ---------------------------------------------------------------------------
__global__ void conv_kernel(const float* __restrict__ x,
                            const float* __restrict__ wq,
                            const float* __restrict__ wk,
                            const float* __restrict__ wv,
                            unsigned short* __restrict__ xb,
                            unsigned short* __restrict__ Wb) {
  int b = blockIdx.x;
  if (b < 6144) {
    int idx4 = (b * 256 + threadIdx.x) * 4;          // < 6291456
    float4 v = *(const float4*)(x + idx4);
    ushort4 o;
    o.x = f2bf(v.x); o.y = f2bf(v.y); o.z = f2bf(v.z); o.w = f2bf(v.w);
    *(ushort4*)(xb + idx4) = o;
  } else {
    int idx4 = ((b - 6144) * 256 + threadIdx.x) * 4; // < 294912
    int z = idx4 / (DOUT * DIN);
    int rem = idx4 - z * (DOUT * DIN);
    const float* src = (z == 0) ? wq : (z == 1) ? wk : wv;
    float4 v = *(const float4*)(src + rem);
    float sc = (z == 0) ? CEXPF : 1.0f;
    ushort4 o;
    o.x = f2bf(v.x * sc); o.y = f2bf(v.y * sc);
    o.z = f2bf(v.z * sc); o.w = f2bf(v.w * sc);
    *(ushort4*)(Wb + idx4) = o;
  }
}

// ---------------------------------------------------------------------------
// Kernel A: QKV projection.  grid (64, 3), block 256 (4 waves).
// Block = 128 x-rows x 128 outcols, K staged in steps of 64.
// Double-buffered LDS (xs[128][64] + ws[128][64] bf16 per buffer = 32 KB),
// global_load_lds staging with source-side XOR swizzle, 2-phase pipeline:
//   STAGE(next) -> compute(cur) -> vmcnt(0) -> barrier.
// Wave w owns x-rows w*32..w*32+31, all 128 outcols: acc[8 mt][2 nt].
// z=0 -> Q (CEXPF folded in Wb), z=1 -> K, z=2 -> Vt via per-wave LDS transpose.
// ---------------------------------------------------------------------------
__launch_bounds__(256, 2)
__global__ void qkv_kernel(const unsigned short* __restrict__ xb,
                           const unsigned short* __restrict__ Wb,
                           unsigned short* __restrict__ Qb,
                           unsigned short* __restrict__ Kb,
                           unsigned short* __restrict__ Vtb) {
  __shared__ unsigned char lds[65536];   // 2 x (xs 16K + ws 16K)

  const int t    = threadIdx.x;
  const int wave = t >> 6;
  const int lane = t & 63;
  const int g    = lane >> 4;
  const int r    = lane & 15;
  const int z    = blockIdx.y;
  const int m0   = blockIdx.x * 128;                 // x-row base
  const unsigned short* Wz = Wb + (size_t)z * DOUT * DIN;

  // stage one K-step: 1024 16B chunks each for xs and ws; 8 DMAs per lane.
  // chunk ci = row*8 + ch; source column-chunk = ch ^ (row&7)  (read-side XOR'd)
  auto stage = [&](int buf, int kb) {
    unsigned char* xs = lds + buf * 32768;
    unsigned char* ws = xs + 16384;
#pragma unroll
    for (int c = 0; c < 4; c++) {
      int ci  = (wave * 4 + c) * 64 + lane;          // 0..1023
      int row = ci >> 3, ch = ci & 7;
      int sc  = (ch ^ (row & 7)) << 3;               // element offset of 16B chunk
      gload_lds16(xb + (size_t)(m0 + row) * DIN + kb + sc,
                  xs + ((wave * 4 + c) << 10) + (lane << 4));
      gload_lds16(Wz + (size_t)row * DIN + kb + sc,
                  ws + ((wave * 4 + c) << 10) + (lane << 4));
    }
  };

  f32x4 acc[8][2];
#pragma unroll
  for (int mt = 0; mt < 8; mt++)
#pragma unroll
    for (int nt = 0; nt < 2; nt++) acc[mt][nt] = 0.f;

  // prologue
  stage(0, 0);
  asm volatile("s_waitcnt vmcnt(0)" ::: "memory");
  __builtin_amdgcn_s_barrier();
  asm volatile("" ::: "memory");

#pragma unroll 1
  for (int s = 0; s < 12; s++) {
    const int cur = s & 1;
    if (s < 11) stage(cur ^ 1, (s + 1) * 64);        // flies under MFMA below
    unsigned char* xs = lds + cur * 32768;
    unsigned char* ws = xs + 16384;
    __builtin_amdgcn_s_setprio(1);
#pragma unroll
    for (int kc = 0; kc < 2; kc++) {
      short8 bfr[2];
#pragma unroll
      for (int nt = 0; nt < 2; nt++) {
        int row = wave * 32 + nt * 16 + r;
        bfr[nt] = *(const short8*)(xs + row * 128 + (((kc * 4 + g) ^ (row & 7)) << 4));
      }
#pragma unroll
      for (int mt = 0; mt < 8; mt++) {
        int oc = mt * 16 + r;
        short8 afr = *(const short8*)(ws + oc * 128 + (((kc * 4 + g) ^ (oc & 7)) << 4));
        acc[mt][0] = __builtin_amdgcn_mfma_f32_16x16x32_bf16(afr, bfr[0], acc[mt][0], 0, 0, 0);
        acc[mt][1] = __builtin_amdgcn_mfma_f32_16x16x32_bf16(afr, bfr[1], acc[mt][1], 0, 0, 0);
      }
    }
    __builtin_amdgcn_s_setprio(0);
    asm volatile("s_waitcnt vmcnt(0)" ::: "memory"); // next-buf loads landed
    __builtin_amdgcn_s_barrier();
    asm volatile("" ::: "memory");
  }

  // D[m = outcol = mt*16+g*4+reg][n = x-row = wave*32+nt*16+r]
  if (z < 2) {
    unsigned short* out = (z == 0) ? Qb : Kb;
#pragma unroll
    for (int mt = 0; mt < 8; mt++)
#pragma unroll
      for (int nt = 0; nt < 2; nt++) {
        ushort4 o;
        o.x = f2bf(acc[mt][nt][0]); o.y = f2bf(acc[mt][nt][1]);
        o.z = f2bf(acc[mt][nt][2]); o.w = f2bf(acc[mt][nt][3]);
        *(ushort4*)(out + (size_t)(m0 + wave * 32 + nt * 16 + r) * DOUT + mt * 16 + g * 4) = o;
      }
  } else {
    // per-wave transpose: ct[32 local rows][136 outcols] ushort
    unsigned short* ct = (unsigned short*)(lds + wave * 8704);
#pragma unroll
    for (int mt = 0; mt < 8; mt++)
#pragma unroll
      for (int nt = 0; nt < 2; nt++) {
        ushort4 o;
        o.x = f2bf(acc[mt][nt][0]); o.y = f2bf(acc[mt][nt][1]);
        o.z = f2bf(acc[mt][nt][2]); o.w = f2bf(acc[mt][nt][3]);
        *(ushort4*)&ct[(nt * 16 + r) * 136 + mt * 16 + g * 4] = o;
      }
    __syncthreads();
    // 4 lanes cooperate per outcol: 64B contiguous store per lane quad
#pragma unroll
    for (int pass = 0; pass < 8; pass++) {
      int col = pass * 16 + (lane >> 2);
      int ch  = lane & 3;
      ushort8v a;
#pragma unroll
      for (int i = 0; i < 8; i++) a[i] = ct[(ch * 8 + i) * 136 + col];
      *(ushort8v*)(Vtb + (size_t)col * SEQ + m0 + wave * 32 + ch * 8) = a;
    }
  }
}

// ---------------------------------------------------------------------------
// Kernel B: flash attention (no online max; scale folded into Q).
// grid (64 qblocks, 8 splits), block 256 (4 waves), wave = 32 q-rows, BN=64.
// S^T = K·Q^T so P^T C-layout packs to b64 LDS writes; staging via
// global_load_lds w/ source-side XOR swizzle.
// Pipelined single-buffer rotation (counted vmcnt, raw s_barrier — no drains):
//   QK(t) -> vmcnt(0)[V(t) landed] -> bar -> issue K(t+1) -> PV(t) -> bar ->
//   issue V(t+1) -> vmcnt(4)[K(t+1) landed, V(t+1) in flight] -> bar
// ---------------------------------------------------------------------------
__launch_bounds__(256, 2)
__global__ void attn_kernel(const unsigned short* __restrict__ Qb,
                            const unsigned short* __restrict__ Kb,
                            const unsigned short* __restrict__ Vtb,
                            float* __restrict__ Opart,
                            float* __restrict__ lpart) {
  __shared__ unsigned char lds[51200];
  unsigned char* Kl = lds;           // [64][128] bf16, 16B chunks XOR-swizzled by row&15
  unsigned char* Vl = lds + 16384;   // [128][64] bf16, 16B chunks XOR-swizzled by d&7

  const int t    = threadIdx.x;
  const int wave = t >> 6;
  const int lane = t & 63;
  const int g    = lane >> 4;
  const int r    = lane & 15;
  unsigned short* Pl = (unsigned short*)(lds + 32768 + wave * 4608);  // [32 q][72 kv]

  const int qb = blockIdx.x;
  const int sp = blockIdx.y;
  const int q0 = qb * 128 + wave * 32;
  const int kvbase = sp * 1024;

  auto stageK = [&](int kv0) {
#pragma unroll
    for (int c = 0; c < 4; c++) {
      int idx = (wave * 4 + c) * 64 + lane;          // 0..1023
      int krow = idx >> 4, kch = idx & 15;
      gload_lds16(Kb + ((size_t)(kv0 + krow) << 7) + ((kch ^ (krow & 15)) << 3),
                  Kl + ((wave * 4 + c) << 10) + (lane << 4));
    }
  };
  auto stageV = [&](int kv0) {
#pragma unroll
    for (int c = 0; c < 4; c++) {
      int idx = (wave * 4 + c) * 64 + lane;          // 0..1023
      int d = idx >> 3, c2 = idx & 7;
      gload_lds16(Vtb + (size_t)d * SEQ + kv0 + ((c2 ^ (d & 7)) << 3),
                  Vl + ((wave * 4 + c) << 10) + (lane << 4));
    }
  };

  // Q B-frags: B[k=din][n=q], n=r, k=g*8+j — contiguous from Qb
  short8 qf[2][4];
#pragma unroll
  for (int nt = 0; nt < 2; nt++)
#pragma unroll
    for (int kc = 0; kc < 4; kc++)
      qf[nt][kc] = *(const short8*)(Qb + (size_t)(q0 + nt * 16 + r) * DOUT + kc * 32 + g * 8);

  // ones B-frag: column n==0 (r==0) holds 1.0bf16
  short8 onesf;
#pragma unroll
  for (int j = 0; j < 8; j++) onesf[j] = (r == 0) ? (short)0x3F80 : (short)0;

  f32x4 oacc[2][8];
  f32x4 lacc[2];
#pragma unroll
  for (int st = 0; st < 2; st++) {
    lacc[st] = 0.f;
#pragma unroll
    for (int n = 0; n < 8; n++) oacc[st][n] = 0.f;
  }

  // prologue: stage tile 0 fully
  stageK(kvbase);
  stageV(kvbase);
  asm volatile("s_waitcnt vmcnt(0)" ::: "memory");
  __builtin_amdgcn_s_barrier();
  asm volatile("" ::: "memory");

#pragma unroll 1
  for (int it = 0; it < 16; it++) {
    // ---- S^T = K Q^T : A=kf (m=kv), B=qf (n=q).  sf[mt][nt] ----
    f32x4 sf[4][2];
#pragma unroll
    for (int mt = 0; mt < 4; mt++)
#pragma unroll
      for (int nt = 0; nt < 2; nt++) sf[mt][nt] = 0.f;
    __builtin_amdgcn_s_setprio(1);
#pragma unroll
    for (int mt = 0; mt < 4; mt++) {
      int row = mt * 16 + r;
#pragma unroll
      for (int kc = 0; kc < 4; kc++) {
        short8 kf = *(const short8*)(Kl + row * 256 + (((kc * 4 + g) ^ (row & 15)) << 4));
        sf[mt][0] = __builtin_amdgcn_mfma_f32_16x16x32_bf16(kf, qf[0][kc], sf[mt][0], 0, 0, 0);
        sf[mt][1] = __builtin_amdgcn_mfma_f32_16x16x32_bf16(kf, qf[1][kc], sf[mt][1], 0, 0, 0);
      }
    }
    __builtin_amdgcn_s_setprio(0);

    // ---- p = exp2(s); P^T lane holds 4 consecutive kv -> packed b64 writes ----
#pragma unroll
    for (int mt = 0; mt < 4; mt++)
#pragma unroll
      for (int nt = 0; nt < 2; nt++) {
        ushort4 p;
        p.x = f2bf(EXP2(sf[mt][nt][0]));
        p.y = f2bf(EXP2(sf[mt][nt][1]));
        p.z = f2bf(EXP2(sf[mt][nt][2]));
        p.w = f2bf(EXP2(sf[mt][nt][3]));
        *(ushort4*)(Pl + (nt * 16 + r) * 72 + mt * 16 + g * 4) = p;
      }
    short8 pf[2][2];
#pragma unroll
    for (int st = 0; st < 2; st++)
#pragma unroll
      for (int c2 = 0; c2 < 2; c2++)
        pf[st][c2] = *(const short8*)(Pl + (st * 16 + r) * 72 + c2 * 32 + g * 8);

    // own V(t) loads are the only outstanding VMEM -> drain them, then release Kl
    asm volatile("s_waitcnt vmcnt(0)" ::: "memory");
    __builtin_amdgcn_s_barrier();          // A: V(t) ready everywhere, Kl free
    asm volatile("" ::: "memory");
    if (it < 15) stageK(kvbase + (it + 1) * 64);   // flies under PV

    // ---- O += P V ; l += P @ ones ----
    __builtin_amdgcn_s_setprio(1);
#pragma unroll
    for (int nt = 0; nt < 8; nt++) {
      int d = nt * 16 + r;
#pragma unroll
      for (int c2 = 0; c2 < 2; c2++) {
        short8 vf = *(const short8*)(Vl + d * 128 + (((c2 * 4 + g) ^ (d & 7)) << 4));
        oacc[0][nt] = __builtin_amdgcn_mfma_f32_16x16x32_bf16(pf[0][c2], vf, oacc[0][nt], 0, 0, 0);
        oacc[1][nt] = __builtin_amdgcn_mfma_f32_16x16x32_bf16(pf[1][c2], vf, oacc[1][nt], 0, 0, 0);
      }
    }
#pragma unroll
    for (int st = 0; st < 2; st++) {
      lacc[st] = __builtin_amdgcn_mfma_f32_16x16x32_bf16(pf[st][0], onesf, lacc[st], 0, 0, 0);
      lacc[st] = __builtin_amdgcn_mfma_f32_16x16x32_bf16(pf[st][1], onesf, lacc[st], 0, 0, 0);
    }
    __builtin_amdgcn_s_setprio(0);

    asm volatile("" ::: "memory");
    __builtin_amdgcn_s_barrier();          // B: Vl free
    asm volatile("" ::: "memory");
    if (it < 15) {
      stageV(kvbase + (it + 1) * 64);      // flies under next QK + exp
      asm volatile("s_waitcnt vmcnt(4)" ::: "memory");  // K(t+1) landed, V(t+1) in flight
      __builtin_amdgcn_s_barrier();        // C: Kl(t+1) ready everywhere
      asm volatile("" ::: "memory");
    }
  }

  // ---- write partials ----
  const size_t pbase = (size_t)sp * SEQ;
#pragma unroll
  for (int st = 0; st < 2; st++)
#pragma unroll
    for (int rr = 0; rr < 4; rr++) {
      int qrow = q0 + st * 16 + g * 4 + rr;
#pragma unroll
      for (int nt = 0; nt < 8; nt++)
        Opart[(pbase + qrow) * DOUT + nt * 16 + r] = oacc[st][nt][rr];
      if (r == 0) lpart[pbase + qrow] = lacc[st][rr];
    }
}

// ---------------------------------------------------------------------------
// Kernel C: combine 8 KV-split partials (plain sum + normalize).
// ---------------------------------------------------------------------------
__global__ void combine_kernel(const float* __restrict__ Opart,
                               const float* __restrict__ lpart,
                               float* __restrict__ out) {
  int idx = blockIdx.x * 256 + threadIdx.x;  // 8192*32
  int s   = idx >> 5;
  int d4  = (idx & 31) * 4;
  float L = 0.f;
  f32x4 acc = 0.f;
#pragma unroll
  for (int p = 0; p < 8; p++) {
    L += lpart[p * SEQ + s];
    acc += *(const f32x4*)(Opart + ((size_t)p * SEQ + s) * DOUT + d4);
  }
  f32x4 res = acc * (1.0f / L);
  *(f32x4*)(out + (size_t)s * DOUT + d4) = res;
}

// ---------------------------------------------------------------------------
extern "C" void kernel_launch(void* const* d_in, const int* in_sizes, int n_in,
                              void* d_out, int out_size, void* d_ws, size_t ws_size,
                              hipStream_t stream) {
  const float* x  = (const float*)d_in[0];
  const float* wq = (const float*)d_in[1];
  const float* wk = (const float*)d_in[2];
  const float* wv = (const float*)d_in[3];
  float* out = (float*)d_out;

  unsigned short* Qb  = (unsigned short*)d_ws;            // 2 MB
  unsigned short* Kb  = Qb + (size_t)SEQ * DOUT;          // 2 MB
  unsigned short* Vtb = Kb + (size_t)SEQ * DOUT;          // 2 MB (transposed)
  float* Opart = (float*)(Vtb + (size_t)SEQ * DOUT);      // 8 * 4 MB
  float* lpart = Opart + (size_t)8 * SEQ * DOUT;          // 256 KB
  // Wb (576 KB) + xb (12.6 MB) alias Opart: dead before attn writes it
  unsigned short* Wb  = (unsigned short*)Opart;
  unsigned short* xb  = Wb + (size_t)3 * DOUT * DIN;
  if (ws_size < (size_t)(6291456 + 33554432 + 262144)) return;

  conv_kernel<<<dim3(6432), 256, 0, stream>>>(x, wq, wk, wv, xb, Wb);
  qkv_kernel<<<dim3(64, 3), 256, 0, stream>>>(xb, Wb, Qb, Kb, Vtb);
  attn_kernel<<<dim3(64, 8), 256, 0, stream>>>(Qb, Kb, Vtb, Opart, lpart);
  combine_kernel<<<dim3(1024), 256, 0, stream>>>(Opart, lpart, out);
}